// Round 5
// baseline (1215.139 us; speedup 1.0000x reference)
//
#include <hip/hip_runtime.h>

// HMM forward, B=64, T=1024, S=512, V=1024.
// One block per batch, thread j owns state j. E = exp(trans) quantized to u8
// with per-row scales folded into P's quantization; E column lives in
// registers (128 uints). Inner loop = v_dot4_i32_i8.
// Round 5: ONE barrier per step (quantize vs per-wave max, consumer-side
// chunk rescale), 8 independent dot accumulators (short dep chains), scales
// via period-8 DPP + readlane (off critical path).

constexpr int Bn = 64, Tn = 1024, Sn = 512;
#define L2E 1.44269504f

__device__ __forceinline__ int dot4(unsigned int e, unsigned int p, int acc) {
#if __has_builtin(__builtin_amdgcn_sdot4)
    return __builtin_amdgcn_sdot4((int)e, (int)p, acc, false);
#elif __has_builtin(__builtin_amdgcn_udot4)
    return (int)__builtin_amdgcn_udot4(e, p, (unsigned)acc, false);
#else
    acc += (int)(e & 0xff) * (int)(p & 0xff);
    acc += (int)((e >> 8) & 0xff) * (int)((p >> 8) & 0xff);
    acc += (int)((e >> 16) & 0xff) * (int)((p >> 16) & 0xff);
    acc += (int)((e >> 24) & 0xff) * (int)((p >> 24) & 0xff);
    return acc;
#endif
}

#if __has_builtin(__builtin_amdgcn_update_dpp)
template <int CTRL>
__device__ __forceinline__ float dpp_fmax(float x) {
    int s = __builtin_bit_cast(int, x);
    int d = __builtin_amdgcn_update_dpp(s, s, CTRL, 0xf, 0xf, false);
    return fmaxf(x, __builtin_bit_cast(float, d));
}
// Full 64-lane max, result uniform via readlane 63.
__device__ __forceinline__ float wave_max64(float x) {
    x = dpp_fmax<0x121>(x);   // row_ror:1
    x = dpp_fmax<0x122>(x);   // row_ror:2
    x = dpp_fmax<0x124>(x);   // row_ror:4
    x = dpp_fmax<0x128>(x);   // row_ror:8
    x = dpp_fmax<0x142>(x);   // row_bcast:15
    x = dpp_fmax<0x143>(x);   // row_bcast:31
    return __builtin_bit_cast(float,
        __builtin_amdgcn_readlane(__builtin_bit_cast(int, x), 63));
}
// Max over a period-8 repeated lane pattern (lanes hold v[lane&7]).
__device__ __forceinline__ float max_of_8_pattern(float x) {
    x = dpp_fmax<0x121>(x);   // row_ror:1
    x = dpp_fmax<0x122>(x);   // row_ror:2
    x = dpp_fmax<0x124>(x);   // row_ror:4 -> 8 consecutive = all residues
    return x;
}
__device__ __forceinline__ float lane_bcast(float x, int l) {
    return __builtin_bit_cast(float,
        __builtin_amdgcn_readlane(__builtin_bit_cast(int, x), l));
}
#else
__device__ __forceinline__ float wave_max64(float x) {
    #pragma unroll
    for (int off = 32; off; off >>= 1) x = fmaxf(x, __shfl_xor(x, off, 64));
    return x;
}
__device__ __forceinline__ float max_of_8_pattern(float x) {
    #pragma unroll
    for (int off = 1; off < 8; off <<= 1) x = fmaxf(x, __shfl_xor(x, off, 64));
    return x;
}
__device__ __forceinline__ float lane_bcast(float x, int l) {
    return __shfl(x, l, 64);
}
#endif

// One block per row i. Quantize row to u8 vs rowmax, dot4 layout:
// uint Eq_u[(i>>2)*512 + j] = rows 4(i>>2)..+3, col j.
__global__ __launch_bounds__(256) void prep_rows(
    const float* __restrict__ trans, unsigned char* __restrict__ Eq,
    float* __restrict__ rowmax)
{
    const int i = blockIdx.x;
    const int j = threadIdx.x;
    const int lane = j & 63, wv = j >> 6;
    float t0 = trans[i * Sn + j];
    float t1 = trans[i * Sn + j + 256];
    float m = fmaxf(t0, t1);
    #pragma unroll
    for (int off = 32; off; off >>= 1) m = fmaxf(m, __shfl_xor(m, off, 64));
    __shared__ float rm[4];
    if (lane == 0) rm[wv] = m;
    __syncthreads();
    m = fmaxf(fmaxf(rm[0], rm[1]), fmaxf(rm[2], rm[3]));
    if (j == 0) rowmax[i] = m;
    int q0 = __float2int_rn(127.f * __expf(t0 - m));
    int q1 = __float2int_rn(127.f * __expf(t1 - m));
    Eq[(i >> 2) * 2048 + j * 4 + (i & 3)] = (unsigned char)q0;
    Eq[(i >> 2) * 2048 + (j + 256) * 4 + (i & 3)] = (unsigned char)q1;
}

// lr[i] = log2(127 * exp(rowmax_i - RM)); C = RM - 2*ln(127)
__global__ __launch_bounds__(512) void prep_scale(
    const float* __restrict__ rowmax, float* __restrict__ lr,
    float* __restrict__ Cp)
{
    const int i = threadIdx.x;
    const int lane = i & 63, wv = i >> 6;
    float m = rowmax[i];
    float rm = m;
    #pragma unroll
    for (int off = 32; off; off >>= 1) rm = fmaxf(rm, __shfl_xor(rm, off, 64));
    __shared__ float red[8];
    if (lane == 0) red[wv] = rm;
    __syncthreads();
    float RM = red[0];
    #pragma unroll
    for (int w = 1; w < 8; ++w) RM = fmaxf(RM, red[w]);
    lr[i] = (m - RM) * L2E + 6.98868469f;           // log2(127)
    if (i == 0) *Cp = RM - 9.68837417f;             // 2*ln(127)
}

__global__ __launch_bounds__(512, 2) void hmm_fwd(
    const int* __restrict__ obs,          // [B, T]
    const float* __restrict__ emis,       // [V, S]
    const float* __restrict__ prior,      // [S]
    const unsigned int* __restrict__ Equ, // packed u8 E, uint view
    const float* __restrict__ lr,         // [S]
    const float* __restrict__ Cp,         // scalar
    float* __restrict__ out)              // [B]
{
    const int b = blockIdx.x;
    const int tid = threadIdx.x;          // state j owned by this thread
    const int lane = tid & 63, wv = tid >> 6;

    __shared__ int obs_s[Tn];
    __shared__ __align__(16) unsigned int Pb[2][Sn / 4];
    __shared__ float redm[2][8];
    __shared__ float reds[8];

    obs_s[tid] = obs[b * Tn + tid];
    obs_s[tid + 512] = obs[b * Tn + 512 + tid];

    // E column: E[k] = rows 4k..4k+3, col tid
    unsigned int E[128];
    #pragma unroll
    for (int k = 0; k < 128; ++k) E[k] = Equ[k * Sn + tid];

    const float lr_t = lr[tid];
    const float C = *Cp;

    __syncthreads();   // obs_s ready

    float a = emis[obs_s[0] * Sn + tid] + prior[tid];
    float e_next = emis[obs_s[1] * Sn + tid];

    for (int t = 1; t < Tn; ++t) {
        const int pb = t & 1;

        // ---- per-wave max (DPP only, no barrier) + quantize + publish
        float mw = wave_max64(a);
        if (lane == 0) redm[pb][wv] = mw;
        int gi = __float2int_rn(exp2f(fmaf(a - mw, L2E, lr_t)));
        ((unsigned char*)Pb[pb])[tid] = (unsigned char)gi;
        __syncthreads();                    // the ONE barrier per step

        // ---- global max + chunk scales (overlaps with dot below)
        float r0 = redm[pb][lane & 7];      // period-8 pattern across lanes
        float m = max_of_8_pattern(r0);     // every lane: max of all 8
        float sv = exp2f((r0 - m) * L2E);   // lane w<8: scale for chunk w

        float e_cur = e_next;
        if (t < Tn - 1) e_next = emis[obs_s[t + 1] * Sn + tid];

        // ---- 8 independent chunk dots (i-chunks of 64), exact i32
        const uint4* P4 = (const uint4*)Pb[pb];
        int idv[8];
        #pragma unroll
        for (int w = 0; w < 8; ++w) {
            int acc = 0;
            #pragma unroll
            for (int c = 0; c < 4; ++c) {
                uint4 p = P4[4 * w + c];    // LDS broadcast
                acc = dot4(E[16 * w + 4 * c + 0], p.x, acc);
                acc = dot4(E[16 * w + 4 * c + 1], p.y, acc);
                acc = dot4(E[16 * w + 4 * c + 2], p.z, acc);
                acc = dot4(E[16 * w + 4 * c + 3], p.w, acc);
            }
            idv[w] = acc;
        }

        // ---- combine with per-chunk scales (scales via readlane -> SGPR)
        float fs = 0.f;
        #pragma unroll
        for (int w = 0; w < 8; ++w)
            fs = fmaf(lane_bcast(sv, w), (float)idv[w], fs);

        a = e_cur + m + C + __logf(fs);
    }

    // ---- out[b] = logsumexp_j(alpha[j]) (once)
    float m = a;
    #pragma unroll
    for (int off = 32; off; off >>= 1) m = fmaxf(m, __shfl_xor(m, off, 64));
    if (lane == 0) redm[0][wv] = m;
    __syncthreads();
    #pragma unroll
    for (int w = 0; w < 8; ++w) m = fmaxf(m, redm[0][w]);

    float s = __expf(a - m);
    #pragma unroll
    for (int off = 32; off; off >>= 1) s += __shfl_xor(s, off, 64);
    if (lane == 0) reds[wv] = s;
    __syncthreads();
    if (tid == 0) {
        float tot = 0.f;
        #pragma unroll
        for (int w = 0; w < 8; ++w) tot += reds[w];
        out[b] = m + __logf(tot);
    }
}

extern "C" void kernel_launch(void* const* d_in, const int* in_sizes, int n_in,
                              void* d_out, int out_size, void* d_ws, size_t ws_size,
                              hipStream_t stream) {
    const int*   obs   = (const int*)d_in[0];
    const float* emis  = (const float*)d_in[1];
    const float* trans = (const float*)d_in[2];
    const float* prior = (const float*)d_in[3];
    float* out = (float*)d_out;

    unsigned char* Eq = (unsigned char*)d_ws;                 // 256 KB
    float* rowmax = (float*)(Eq + Sn * Sn);                   // 2 KB
    float* lr     = rowmax + Sn;                              // 2 KB
    float* Cp     = lr + Sn;                                  // 4 B

    prep_rows<<<Sn, 256, 0, stream>>>(trans, Eq, rowmax);
    prep_scale<<<1, Sn, 0, stream>>>(rowmax, lr, Cp);
    hmm_fwd<<<Bn, Sn, 0, stream>>>(obs, emis, prior,
                                   (const unsigned int*)Eq, lr, Cp, out);
}

// Round 6
// 1115.611 us; speedup vs baseline: 1.0892x; 1.0892x over previous
//
#include <hip/hip_runtime.h>

// HMM forward, B=64, T=1024, S=512, V=1024.
// One block per batch. E = exp(trans) quantized u8 (per-row scale, folded into
// P quantization) stored as MFMA B-fragments; inner product via
// v_mfma_i32_16x16x64_i8 (M=1 used, rows 1..15 ignored).
// Per step: exact block max -> quantize P -> LDS A row -> 8 ds_read_b128 ->
// 32 MFMA/wave -> LDS redistribute row 0 -> log + emis.

constexpr int Bn = 64, Tn = 1024, Sn = 512;
#define L2E 1.44269504f
#define AS 592           // A-row LDS stride bytes (16B aligned, 592/4=148)

typedef int v4i __attribute__((ext_vector_type(4)));

#if __has_builtin(__builtin_amdgcn_update_dpp)
template <int CTRL>
__device__ __forceinline__ float dpp_fmax(float x) {
    int s = __builtin_bit_cast(int, x);
    int d = __builtin_amdgcn_update_dpp(s, s, CTRL, 0xf, 0xf, false);
    return fmaxf(x, __builtin_bit_cast(float, d));
}
__device__ __forceinline__ float wave_max64(float x) {
    x = dpp_fmax<0x121>(x);   // row_ror:1
    x = dpp_fmax<0x122>(x);   // row_ror:2
    x = dpp_fmax<0x124>(x);   // row_ror:4
    x = dpp_fmax<0x128>(x);   // row_ror:8
    x = dpp_fmax<0x142>(x);   // row_bcast:15
    x = dpp_fmax<0x143>(x);   // row_bcast:31
    return __builtin_bit_cast(float,
        __builtin_amdgcn_readlane(__builtin_bit_cast(int, x), 63));
}
#else
__device__ __forceinline__ float wave_max64(float x) {
    #pragma unroll
    for (int off = 32; off; off >>= 1) x = fmaxf(x, __shfl_xor(x, off, 64));
    return x;
}
#endif

// Eq value for (row i, col c) -> B-fragment byte address:
// frag = (c>>4)*8 + (i>>6); lane = ((i>>4)&3)*16 + (c&15); byte = i&15
__device__ __forceinline__ int bfrag_addr(int i, int c) {
    return ((((c >> 4) * 8 + (i >> 6)) * 64) + ((i >> 4) & 3) * 16 + (c & 15)) * 16
           + (i & 15);
}

// One block per row i: rowmax + quantize row to u8, scatter into B-frag layout.
__global__ __launch_bounds__(256) void prep_rows(
    const float* __restrict__ trans, unsigned char* __restrict__ EqB,
    float* __restrict__ rowmax)
{
    const int i = blockIdx.x;
    const int j = threadIdx.x;
    const int lane = j & 63, wv = j >> 6;
    float t0 = trans[i * Sn + j];
    float t1 = trans[i * Sn + j + 256];
    float m = fmaxf(t0, t1);
    #pragma unroll
    for (int off = 32; off; off >>= 1) m = fmaxf(m, __shfl_xor(m, off, 64));
    __shared__ float rm[4];
    if (lane == 0) rm[wv] = m;
    __syncthreads();
    m = fmaxf(fmaxf(rm[0], rm[1]), fmaxf(rm[2], rm[3]));
    if (j == 0) rowmax[i] = m;
    int q0 = __float2int_rn(127.f * __expf(t0 - m));
    int q1 = __float2int_rn(127.f * __expf(t1 - m));
    EqB[bfrag_addr(i, j)] = (unsigned char)q0;
    EqB[bfrag_addr(i, j + 256)] = (unsigned char)q1;
}

// lr[i] = log2(127 * exp(rowmax_i - RM)); C = RM - 2*ln(127)
__global__ __launch_bounds__(512) void prep_scale(
    const float* __restrict__ rowmax, float* __restrict__ lr,
    float* __restrict__ Cp)
{
    const int i = threadIdx.x;
    const int lane = i & 63, wv = i >> 6;
    float m = rowmax[i];
    float rm = m;
    #pragma unroll
    for (int off = 32; off; off >>= 1) rm = fmaxf(rm, __shfl_xor(rm, off, 64));
    __shared__ float red[8];
    if (lane == 0) red[wv] = rm;
    __syncthreads();
    float RM = red[0];
    #pragma unroll
    for (int w = 1; w < 8; ++w) RM = fmaxf(RM, red[w]);
    lr[i] = (m - RM) * L2E + 6.98868469f;           // log2(127)
    if (i == 0) *Cp = RM - 9.68837417f;             // 2*ln(127)
}

__global__ __launch_bounds__(512, 2) void hmm_fwd(
    const int* __restrict__ obs,          // [B, T]
    const float* __restrict__ emis,       // [V, S]
    const float* __restrict__ prior,      // [S]
    const v4i* __restrict__ EqB4,         // B-fragments, 16B per (frag,lane)
    const float* __restrict__ lr,         // [S]
    const float* __restrict__ Cp,         // scalar
    float* __restrict__ out)              // [B]
{
    const int b = blockIdx.x;
    const int tid = threadIdx.x;          // state j owned by this thread
    const int lane = tid & 63, wv = tid >> 6;
    const int m16 = lane & 15, q = lane >> 4;

    __shared__ int obs_s[Tn];
    __shared__ __align__(16) unsigned char PqA[16 * AS];
    __shared__ int Cid[Sn];
    __shared__ __align__(32) float redm[2][8];
    __shared__ float reds[8];

    obs_s[tid] = obs[b * Tn + tid];
    obs_s[tid + 512] = obs[b * Tn + 512 + tid];

    // B-fragments: Bf[tau][kap] = E rows kap*64+q*16+(0..15), cols wv*64+tau*16+m16
    v4i Bf[4][8];
    #pragma unroll
    for (int tau = 0; tau < 4; ++tau)
        #pragma unroll
        for (int kap = 0; kap < 8; ++kap)
            Bf[tau][kap] = EqB4[((wv * 4 + tau) * 8 + kap) * 64 + lane];

    const float lr_t = lr[tid];
    const float C = *Cp;

    __syncthreads();   // obs_s ready

    float a = emis[obs_s[0] * Sn + tid] + prior[tid];
    float e_next = emis[obs_s[1] * Sn + tid];

    const v4i* Aled = (const v4i*)(PqA + m16 * AS + q * 16);  // + kap*64 bytes

    for (int t = 1; t < Tn; ++t) {
        const int pb = t & 1;

        // ---- exact block max
        float mw = wave_max64(a);
        if (lane == 0) redm[pb][wv] = mw;
        __syncthreads();                          // barrier 1
        const float4* rmv = (const float4*)redm[pb];
        float4 r0 = rmv[0], r1 = rmv[1];
        float m = fmaxf(fmaxf(fmaxf(r0.x, r0.y), fmaxf(r0.z, r0.w)),
                        fmaxf(fmaxf(r1.x, r1.y), fmaxf(r1.z, r1.w)));

        // ---- quantize P (u8, row-scale folded) into A row 0 (linear k)
        int gi = __float2int_rn(exp2f(fmaf(a - m, L2E, lr_t)));
        PqA[tid] = (unsigned char)gi;
        __syncthreads();                          // barrier 2

        float e_cur = e_next;
        if (t < Tn - 1) e_next = emis[obs_s[t + 1] * Sn + tid];

        // ---- A-fragments (rows 1..15 garbage -> C rows 1..15 ignored)
        v4i Af[8];
        #pragma unroll
        for (int kap = 0; kap < 8; ++kap) Af[kap] = Aled[kap * 4];  // +64B each

        // ---- 4 n-tiles x 8 k-chunks of mfma_i32_16x16x64_i8
        v4i acc[4];
        #pragma unroll
        for (int tau = 0; tau < 4; ++tau) {
            v4i z = {0, 0, 0, 0};
            #pragma unroll
            for (int kap = 0; kap < 8; ++kap)
                z = __builtin_amdgcn_mfma_i32_16x16x64_i8(Af[kap], Bf[tau][kap],
                                                          z, 0, 0, 0);
            acc[tau] = z;
        }

        // ---- redistribute C row 0: lanes 0..15 hold (tau) cols in acc.x
        if (lane < 16) {
            #pragma unroll
            for (int tau = 0; tau < 4; ++tau)
                Cid[wv * 64 + tau * 16 + lane] = acc[tau].x;
        }
        __syncthreads();                          // barrier 3
        int idot = Cid[tid];

        a = e_cur + m + C + __logf((float)idot);
    }

    // ---- out[b] = logsumexp_j(alpha[j])
    float m = a;
    #pragma unroll
    for (int off = 32; off; off >>= 1) m = fmaxf(m, __shfl_xor(m, off, 64));
    if (lane == 0) redm[0][wv] = m;
    __syncthreads();
    #pragma unroll
    for (int w = 0; w < 8; ++w) m = fmaxf(m, redm[0][w]);

    float s = __expf(a - m);
    #pragma unroll
    for (int off = 32; off; off >>= 1) s += __shfl_xor(s, off, 64);
    if (lane == 0) reds[wv] = s;
    __syncthreads();
    if (tid == 0) {
        float tot = 0.f;
        #pragma unroll
        for (int w = 0; w < 8; ++w) tot += reds[w];
        out[b] = m + __logf(tot);
    }
}

extern "C" void kernel_launch(void* const* d_in, const int* in_sizes, int n_in,
                              void* d_out, int out_size, void* d_ws, size_t ws_size,
                              hipStream_t stream) {
    const int*   obs   = (const int*)d_in[0];
    const float* emis  = (const float*)d_in[1];
    const float* trans = (const float*)d_in[2];
    const float* prior = (const float*)d_in[3];
    float* out = (float*)d_out;

    unsigned char* EqB = (unsigned char*)d_ws;                // 256 KB
    float* rowmax = (float*)(EqB + Sn * Sn);                  // 2 KB
    float* lr     = rowmax + Sn;                              // 2 KB
    float* Cp     = lr + Sn;                                  // 4 B

    prep_rows<<<Sn, 256, 0, stream>>>(trans, EqB, rowmax);
    prep_scale<<<1, Sn, 0, stream>>>(rowmax, lr, Cp);
    hmm_fwd<<<Bn, Sn, 0, stream>>>(obs, emis, prior,
                                   (const v4i*)EqB, lr, Cp, out);
}

// Round 7
// 1009.980 us; speedup vs baseline: 1.2031x; 1.1046x over previous
//
#include <hip/hip_runtime.h>

// HMM forward, B=64, T=1024, S=512, V=1024.
// One block per batch. E = exp(trans) quantized u8 (per-row scale folded into
// P's quantization) as MFMA B-fragments in registers (128 VGPRs).
// Inner product: v_mfma_i32_16x16x64_i8 with ALL 16 A-rows identical
// (quad-broadcast reads of the linear P byte vector) -> every C row is the
// result -> thread reads acc[lane>>4].x in-register. No C redistribute,
// no strided A staging, zero LDS bank conflicts, 2 barriers/step.

constexpr int Bn = 64, Tn = 1024, Sn = 512;
#define L2E 1.44269504f

typedef int v4i __attribute__((ext_vector_type(4)));

#if __has_builtin(__builtin_amdgcn_update_dpp)
template <int CTRL>
__device__ __forceinline__ float dpp_fmax(float x) {
    int s = __builtin_bit_cast(int, x);
    int d = __builtin_amdgcn_update_dpp(s, s, CTRL, 0xf, 0xf, false);
    return fmaxf(x, __builtin_bit_cast(float, d));
}
__device__ __forceinline__ float wave_max64(float x) {
    x = dpp_fmax<0x121>(x);   // row_ror:1
    x = dpp_fmax<0x122>(x);   // row_ror:2
    x = dpp_fmax<0x124>(x);   // row_ror:4
    x = dpp_fmax<0x128>(x);   // row_ror:8
    x = dpp_fmax<0x142>(x);   // row_bcast:15
    x = dpp_fmax<0x143>(x);   // row_bcast:31
    return __builtin_bit_cast(float,
        __builtin_amdgcn_readlane(__builtin_bit_cast(int, x), 63));
}
// Max over period-8 lane pattern (lane holds v[lane&7]) -> all lanes get max.
__device__ __forceinline__ float max_of_8_pattern(float x) {
    x = dpp_fmax<0x121>(x);
    x = dpp_fmax<0x122>(x);
    x = dpp_fmax<0x124>(x);
    return x;
}
#else
__device__ __forceinline__ float wave_max64(float x) {
    #pragma unroll
    for (int off = 32; off; off >>= 1) x = fmaxf(x, __shfl_xor(x, off, 64));
    return x;
}
__device__ __forceinline__ float max_of_8_pattern(float x) {
    #pragma unroll
    for (int off = 1; off < 8; off <<= 1) x = fmaxf(x, __shfl_xor(x, off, 64));
    return x;
}
#endif

// Eq value for (row i, col c) -> B-fragment byte address:
// frag = (c>>4)*8 + (i>>6); lane = ((i>>4)&3)*16 + (c&15); byte = i&15
__device__ __forceinline__ int bfrag_addr(int i, int c) {
    return ((((c >> 4) * 8 + (i >> 6)) * 64) + ((i >> 4) & 3) * 16 + (c & 15)) * 16
           + (i & 15);
}

// One block per row i: rowmax + quantize row to u8, scatter into B-frag layout.
__global__ __launch_bounds__(256) void prep_rows(
    const float* __restrict__ trans, unsigned char* __restrict__ EqB,
    float* __restrict__ rowmax)
{
    const int i = blockIdx.x;
    const int j = threadIdx.x;
    const int lane = j & 63, wv = j >> 6;
    float t0 = trans[i * Sn + j];
    float t1 = trans[i * Sn + j + 256];
    float m = fmaxf(t0, t1);
    #pragma unroll
    for (int off = 32; off; off >>= 1) m = fmaxf(m, __shfl_xor(m, off, 64));
    __shared__ float rm[4];
    if (lane == 0) rm[wv] = m;
    __syncthreads();
    m = fmaxf(fmaxf(rm[0], rm[1]), fmaxf(rm[2], rm[3]));
    if (j == 0) rowmax[i] = m;
    int q0 = __float2int_rn(127.f * __expf(t0 - m));
    int q1 = __float2int_rn(127.f * __expf(t1 - m));
    EqB[bfrag_addr(i, j)] = (unsigned char)q0;
    EqB[bfrag_addr(i, j + 256)] = (unsigned char)q1;
}

// lr[i] = log2(127 * exp(rowmax_i - RM)); C = RM - 2*ln(127)
__global__ __launch_bounds__(512) void prep_scale(
    const float* __restrict__ rowmax, float* __restrict__ lr,
    float* __restrict__ Cp)
{
    const int i = threadIdx.x;
    const int lane = i & 63, wv = i >> 6;
    float m = rowmax[i];
    float rm = m;
    #pragma unroll
    for (int off = 32; off; off >>= 1) rm = fmaxf(rm, __shfl_xor(rm, off, 64));
    __shared__ float red[8];
    if (lane == 0) red[wv] = rm;
    __syncthreads();
    float RM = red[0];
    #pragma unroll
    for (int w = 1; w < 8; ++w) RM = fmaxf(RM, red[w]);
    lr[i] = (m - RM) * L2E + 6.98868469f;           // log2(127)
    if (i == 0) *Cp = RM - 9.68837417f;             // 2*ln(127)
}

__global__ __launch_bounds__(512, 2) void hmm_fwd(
    const int* __restrict__ obs,          // [B, T]
    const float* __restrict__ emis,       // [V, S]
    const float* __restrict__ prior,      // [S]
    const v4i* __restrict__ EqB4,         // B-fragments, 16B per (frag,lane)
    const float* __restrict__ lr,         // [S]
    const float* __restrict__ Cp,         // scalar
    float* __restrict__ out)              // [B]
{
    const int b = blockIdx.x;
    const int tid = threadIdx.x;          // state j owned by this thread
    const int lane = tid & 63, wv = tid >> 6;
    const int q = lane >> 4;

    __shared__ int obs_s[Tn];
    __shared__ __align__(16) unsigned char Pq[2][Sn];
    __shared__ float redm[2][8];
    __shared__ float reds[8];

    obs_s[tid] = obs[b * Tn + tid];
    obs_s[tid + 512] = obs[b * Tn + 512 + tid];

    // B-fragments: Bf[tau][kap] = E rows kap*64+(16k-subchunks), cols wv*64+tau*16+(lane&15)
    v4i Bf[4][8];
    #pragma unroll
    for (int tau = 0; tau < 4; ++tau)
        #pragma unroll
        for (int kap = 0; kap < 8; ++kap)
            Bf[tau][kap] = EqB4[((wv * 4 + tau) * 8 + kap) * 64 + lane];

    const float lr_t = lr[tid];
    const float C = *Cp;

    __syncthreads();   // obs_s ready

    float a = emis[obs_s[0] * Sn + tid] + prior[tid];
    float e_next = emis[obs_s[1] * Sn + tid];

    for (int t = 1; t < Tn; ++t) {
        const int pb = t & 1;

        // ---- exact block max: DPP in-wave, one b32 LDS round-trip cross-wave
        float mw = wave_max64(a);
        if (lane == 0) redm[pb][wv] = mw;
        __syncthreads();                          // barrier 1
        float m = max_of_8_pattern(redm[pb][lane & 7]);

        // ---- quantize P (u8, row-scale folded) into linear byte vector
        int gi = __float2int_rn(exp2f(fmaf(a - m, L2E, lr_t)));
        Pq[pb][tid] = (unsigned char)gi;
        __syncthreads();                          // barrier 2

        float e_cur = e_next;
        if (t < Tn - 1) e_next = emis[obs_s[t + 1] * Sn + tid];

        // ---- A-fragments: quad-broadcast reads of P (all 16 A-rows identical)
        const unsigned char* Pbase = Pq[pb] + q * 16;
        v4i Af[8];
        #pragma unroll
        for (int kap = 0; kap < 8; ++kap)
            Af[kap] = *(const v4i*)(Pbase + kap * 64);

        // ---- 4 n-tiles x 8 k-chunks of mfma_i32_16x16x64_i8
        v4i acc[4];
        #pragma unroll
        for (int tau = 0; tau < 4; ++tau) {
            v4i z = {0, 0, 0, 0};
            #pragma unroll
            for (int kap = 0; kap < 8; ++kap)
                z = __builtin_amdgcn_mfma_i32_16x16x64_i8(Af[kap], Bf[tau][kap],
                                                          z, 0, 0, 0);
            acc[tau] = z;
        }

        // ---- every C row equals the result: select tau = lane>>4 in-register
        int idot = (lane < 16) ? acc[0].x
                 : (lane < 32) ? acc[1].x
                 : (lane < 48) ? acc[2].x
                               : acc[3].x;

        a = e_cur + m + C + __logf((float)idot);
    }

    // ---- out[b] = logsumexp_j(alpha[j])
    float m = a;
    #pragma unroll
    for (int off = 32; off; off >>= 1) m = fmaxf(m, __shfl_xor(m, off, 64));
    if (lane == 0) redm[0][wv] = m;
    __syncthreads();
    #pragma unroll
    for (int w = 0; w < 8; ++w) m = fmaxf(m, redm[0][w]);

    float s = __expf(a - m);
    #pragma unroll
    for (int off = 32; off; off >>= 1) s += __shfl_xor(s, off, 64);
    if (lane == 0) reds[wv] = s;
    __syncthreads();
    if (tid == 0) {
        float tot = 0.f;
        #pragma unroll
        for (int w = 0; w < 8; ++w) tot += reds[w];
        out[b] = m + __logf(tot);
    }
}

extern "C" void kernel_launch(void* const* d_in, const int* in_sizes, int n_in,
                              void* d_out, int out_size, void* d_ws, size_t ws_size,
                              hipStream_t stream) {
    const int*   obs   = (const int*)d_in[0];
    const float* emis  = (const float*)d_in[1];
    const float* trans = (const float*)d_in[2];
    const float* prior = (const float*)d_in[3];
    float* out = (float*)d_out;

    unsigned char* EqB = (unsigned char*)d_ws;                // 256 KB
    float* rowmax = (float*)(EqB + Sn * Sn);                  // 2 KB
    float* lr     = rowmax + Sn;                              // 2 KB
    float* Cp     = lr + Sn;                                  // 4 B

    prep_rows<<<Sn, 256, 0, stream>>>(trans, EqB, rowmax);
    prep_scale<<<1, Sn, 0, stream>>>(rowmax, lr, Cp);
    hmm_fwd<<<Bn, Sn, 0, stream>>>(obs, emis, prior,
                                   (const v4i*)EqB, lr, Cp, out);
}